// Round 1
// baseline (271.219 us; speedup 1.0000x reference)
//
#include <hip/hip_runtime.h>
#include <stdint.h>

#define HID 30
#define NCLS 10
#define SEQ 784
#define NBATCH 16384
#define TCH 112      // time steps per LDS stage
#define NSTAGE 7     // 7 * 112 = 784
#define XPAD 116     // padded LDS row stride in floats (multiple of 4)

typedef __bf16 bf16x8 __attribute__((ext_vector_type(8)));
typedef float f32x4 __attribute__((ext_vector_type(4)));
typedef uint32_t u32x4 __attribute__((ext_vector_type(4)));

static __device__ __forceinline__ bf16x8 mkfrag(uint32_t a, uint32_t b, uint32_t c, uint32_t d) {
    u32x4 t = {a, b, c, d};
    return __builtin_bit_cast(bf16x8, t);
}

// pack top-16-bits of two fp32 (bf16 truncation): low16 = even element, high16 = odd
static __device__ __forceinline__ uint32_t pk_hi(uint32_t odd_bits, uint32_t even_bits) {
    return __builtin_amdgcn_perm(odd_bits, even_bits, 0x07060302u);
}

// 3-way bf16 split of one fp32: returns raw fp32 bit patterns whose top 16 bits
// are the hi / mid / lo bf16 components (hi+mid+lo == f up to 2^-24 rel).
static __device__ __forceinline__ void split3(float f, uint32_t& uh, uint32_t& um, uint32_t& ul) {
    uint32_t uf = __float_as_uint(f);
    uint32_t hb = uf & 0xFFFF0000u;
    float r = f - __uint_as_float(hb);
    uint32_t ur = __float_as_uint(r);
    uint32_t mb = ur & 0xFFFF0000u;
    float lo = r - __uint_as_float(mb);
    uh = uf; um = ur; ul = __float_as_uint(lo);
}

__launch_bounds__(64, 1)
__global__ void rnn_scan_kernel(const float* __restrict__ inp,
                                const float* __restrict__ W_ih,
                                const float* __restrict__ W_hh,
                                const float* __restrict__ b_mod,
                                const float* __restrict__ W_lin,
                                const float* __restrict__ b_lin,
                                float* __restrict__ out)
{
    __shared__ __align__(16) float xs[16 * XPAD];

    const int lane = threadIdx.x;   // 0..63, one wave per block
    const int q = lane >> 4;        // k-quad: this lane holds k = 8q..8q+7 of A/B frags
    const int n = lane & 15;        // batch column within the wave's 16-batch tile
    const int b0 = blockIdx.x * 16; // this block's batch base

    // ---- A fragments: W_aug [32x32], row-permuted so D->B is lane-local ----
    // W_aug[i][j] = W_hh[i][j] (i,j<30) ; W_aug[i][30] = W_ih[i] ; else 0.
    // tile1 m-position (lane&15)=n holds W_aug row i1 = 8*(n>>2)+(n&3)
    // tile2 holds i2 = i1 + 4. Then D1 regs r = z[8q+r], D2 regs r = z[8q+4+r],
    // i.e. after modReLU each lane holds exactly h[j], j = 8q..8q+7 = its B frag.
    const int i1 = 8 * (n >> 2) + (n & 3);
    const int i2 = i1 + 4;

    uint32_t a1h[4], a1m[4], a1l[4], a2h[4], a2m[4], a2l[4];
    #pragma unroll
    for (int p = 0; p < 4; ++p) {
        uint32_t h1[2], m1[2], l1[2], h2[2], m2[2], l2[2];
        #pragma unroll
        for (int e = 0; e < 2; ++e) {
            const int j = 8 * q + 2 * p + e;
            float w1 = 0.f, w2 = 0.f;
            if (j < HID) {
                w1 = W_hh[i1 * HID + j];
                if (i2 < HID) w2 = W_hh[i2 * HID + j];
            } else if (j == HID) {
                w1 = W_ih[i1];
                if (i2 < HID) w2 = W_ih[i2];
            }
            split3(w1, h1[e], m1[e], l1[e]);
            split3(w2, h2[e], m2[e], l2[e]);
        }
        a1h[p] = pk_hi(h1[1], h1[0]); a1m[p] = pk_hi(m1[1], m1[0]); a1l[p] = pk_hi(l1[1], l1[0]);
        a2h[p] = pk_hi(h2[1], h2[0]); a2m[p] = pk_hi(m2[1], m2[0]); a2l[p] = pk_hi(l2[1], l2[0]);
    }
    const bf16x8 A1h = mkfrag(a1h[0], a1h[1], a1h[2], a1h[3]);
    const bf16x8 A1m = mkfrag(a1m[0], a1m[1], a1m[2], a1m[3]);
    const bf16x8 A1l = mkfrag(a1l[0], a1l[1], a1l[2], a1l[3]);
    const bf16x8 A2h = mkfrag(a2h[0], a2h[1], a2h[2], a2h[3]);
    const bf16x8 A2m = mkfrag(a2m[0], a2m[1], a2m[2], a2m[3]);
    const bf16x8 A2l = mkfrag(a2l[0], a2l[1], a2l[2], a2l[3]);

    // b_mod for this lane's 8 output rows (i = 8q+r and 8q+4+r); pad rows -> 0
    float bm[8];
    #pragma unroll
    for (int r = 0; r < 4; ++r) {
        const int ia = 8 * q + r;        // <= 27, always valid
        const int ib = 8 * q + 4 + r;    // up to 31
        bm[r] = b_mod[ia];
        bm[4 + r] = (ib < HID) ? b_mod[ib] : 0.f;
    }

    float h[8];
    #pragma unroll
    for (int r = 0; r < 8; ++r) h[r] = 0.f;

    const bool isq3 = (q == 3);

    for (int s = 0; s < NSTAGE; ++s) {
        // ---- stage TCH steps of inputs for 16 batch rows into LDS ----
        // 16 rows * 28 float4 = 448 float4 = 7 per thread; coalesced along t.
        #pragma unroll
        for (int r = 0; r < 7; ++r) {
            const int idx = r * 64 + lane;
            const int bl = idx / 28;
            const int t4 = idx % 28;
            const float4 v = *(const float4*)(inp + (size_t)(b0 + bl) * SEQ + s * TCH + t4 * 4);
            *(float4*)(&xs[bl * XPAD + t4 * 4]) = v;
        }
        __syncthreads();

        const float* xrow = &xs[n * XPAD];
        for (int t4 = 0; t4 < 28; ++t4) {
            const float4 xv = *(const float4*)(xrow + t4 * 4); // broadcast across q
            #pragma unroll
            for (int u = 0; u < 4; ++u) {
                const float x = (u == 0) ? xv.x : (u == 1) ? xv.y : (u == 2) ? xv.z : xv.w;
                // h_aug: j=30 slot (q==3, k=6) <- x_t ; j=31 slot <- 0
                const float hv6 = isq3 ? x : h[6];
                const float hv7 = isq3 ? 0.f : h[7];
                // 3-way split + pack B fragments
                uint32_t uh[8], um[8], ul[8];
                #pragma unroll
                for (int k = 0; k < 8; ++k) {
                    const float f = (k == 6) ? hv6 : (k == 7) ? hv7 : h[k];
                    split3(f, uh[k], um[k], ul[k]);
                }
                uint32_t bh[4], bmm[4], bl_[4];
                #pragma unroll
                for (int p = 0; p < 4; ++p) {
                    bh[p]  = pk_hi(uh[2*p+1], uh[2*p]);
                    bmm[p] = pk_hi(um[2*p+1], um[2*p]);
                    bl_[p] = pk_hi(ul[2*p+1], ul[2*p]);
                }
                const bf16x8 Bh = mkfrag(bh[0], bh[1], bh[2], bh[3]);
                const bf16x8 Bm = mkfrag(bmm[0], bmm[1], bmm[2], bmm[3]);
                const bf16x8 Bl = mkfrag(bl_[0], bl_[1], bl_[2], bl_[3]);

                f32x4 d1 = {0.f, 0.f, 0.f, 0.f};
                f32x4 d2 = {0.f, 0.f, 0.f, 0.f};
                // keep all cross terms >= 2^-16: hh, hm, mh, hl, lh, mm
                d1 = __builtin_amdgcn_mfma_f32_16x16x32_bf16(A1h, Bh, d1, 0, 0, 0);
                d2 = __builtin_amdgcn_mfma_f32_16x16x32_bf16(A2h, Bh, d2, 0, 0, 0);
                d1 = __builtin_amdgcn_mfma_f32_16x16x32_bf16(A1h, Bm, d1, 0, 0, 0);
                d2 = __builtin_amdgcn_mfma_f32_16x16x32_bf16(A2h, Bm, d2, 0, 0, 0);
                d1 = __builtin_amdgcn_mfma_f32_16x16x32_bf16(A1m, Bh, d1, 0, 0, 0);
                d2 = __builtin_amdgcn_mfma_f32_16x16x32_bf16(A2m, Bh, d2, 0, 0, 0);
                d1 = __builtin_amdgcn_mfma_f32_16x16x32_bf16(A1h, Bl, d1, 0, 0, 0);
                d2 = __builtin_amdgcn_mfma_f32_16x16x32_bf16(A2h, Bl, d2, 0, 0, 0);
                d1 = __builtin_amdgcn_mfma_f32_16x16x32_bf16(A1l, Bh, d1, 0, 0, 0);
                d2 = __builtin_amdgcn_mfma_f32_16x16x32_bf16(A2l, Bh, d2, 0, 0, 0);
                d1 = __builtin_amdgcn_mfma_f32_16x16x32_bf16(A1m, Bm, d1, 0, 0, 0);
                d2 = __builtin_amdgcn_mfma_f32_16x16x32_bf16(A2m, Bm, d2, 0, 0, 0);

                // modReLU: h = copysign(max(|z| + b, 0), z)  (3 VALU ops/elem)
                #pragma unroll
                for (int r = 0; r < 4; ++r) {
                    const float z1 = d1[r];
                    h[r] = __builtin_copysignf(fmaxf(fabsf(z1) + bm[r], 0.f), z1);
                    const float z2 = d2[r];
                    h[4 + r] = __builtin_copysignf(fmaxf(fabsf(z2) + bm[4 + r], 0.f), z2);
                }
            }
        }
        __syncthreads();
    }

    // ---- final linear: logits = h_final @ W_lin^T + b_lin ----
    // lane holds h[j], j = 8q+k; reduce partial dot over the 4 q-groups.
    float acc[NCLS];
    #pragma unroll
    for (int c = 0; c < NCLS; ++c) {
        float p = 0.f;
        #pragma unroll
        for (int k = 0; k < 8; ++k) {
            const int j = 8 * q + k;
            if (j < HID) p += W_lin[c * HID + j] * h[k];
        }
        p += __shfl_xor(p, 16, 64);
        p += __shfl_xor(p, 32, 64);
        acc[c] = p + b_lin[c];
    }
    if (q == 0) {
        #pragma unroll
        for (int c = 0; c < NCLS; ++c)
            out[(size_t)(b0 + n) * NCLS + c] = acc[c];
    }
}

extern "C" void kernel_launch(void* const* d_in, const int* in_sizes, int n_in,
                              void* d_out, int out_size, void* d_ws, size_t ws_size,
                              hipStream_t stream) {
    const float* inp   = (const float*)d_in[0];
    const float* W_ih  = (const float*)d_in[1];
    const float* W_hh  = (const float*)d_in[2];
    const float* b_mod = (const float*)d_in[3];
    const float* W_lin = (const float*)d_in[4];
    const float* b_lin = (const float*)d_in[5];
    float* out = (float*)d_out;

    dim3 grid(NBATCH / 16);  // 1024 blocks, 16 batch rows each
    dim3 block(64);          // one wave per block
    hipLaunchKernelGGL(rnn_scan_kernel, grid, block, 0, stream,
                       inp, W_ih, W_hh, b_mod, W_lin, b_lin, out);
}